// Round 7
// baseline (4419.867 us; speedup 1.0000x reference)
//
#include <hip/hip_runtime.h>
#include <math.h>

typedef unsigned short ushort_t;
typedef _Float16 f16x8 __attribute__((ext_vector_type(8)));
typedef float f32x4 __attribute__((ext_vector_type(4)));

#define B_ 16
#define NC_ 3
#define NF_ 64
#define NL_ 5
#define HW_ 256
#define PAD_ 7

__device__ __forceinline__ ushort_t f2h(float f) {
  union { _Float16 h; ushort_t u; } v;
  v.h = (_Float16)f;           // v_cvt_f16_f32, round-to-nearest-even
  return v.u;
}

// ---------- weight prep: normalize, scale, cast fp16, emit FRAGMENT-LINEAR layout ----------
// wt index = ((((l*16+b)*9 + t)*2 + k)*4 + n)*512 + lane*8 + j
// holding weight[oc = n*16 + (lane&15)][ic = k*32 + (lane>>4)*8 + j] for tap t=(ky*3+kx)
__global__ void prep_body_k(const float* __restrict__ bw, ushort_t* __restrict__ wt, float cw) {
  int idx = blockIdx.x * 256 + threadIdx.x;
  const int total = NL_ * B_ * 9 * 2 * 4 * 64 * 8;
  if (idx >= total) return;
  int j = idx & 7;
  int lane = (idx >> 3) & 63;
  int n = (idx >> 9) & 3;
  int k = (idx >> 11) & 1;
  int rest = idx >> 12;          // (l*16+b)*9 + t
  int t = rest % 9;
  int t2 = rest / 9;
  int b = t2 & 15;
  int l = t2 >> 4;
  int oc = n * 16 + (lane & 15);
  int ic = k * 32 + (lane >> 4) * 8 + j;
  int ky = t / 3, kx = t % 3;
  float w = bw[(((((size_t)l * B_ + b) * NF_ + oc) * NF_ + ic) * 3 + ky) * 3 + kx];
  wt[idx] = f2h(w * cw);
}

__global__ void prep_tail_k(const float* __restrict__ tw, ushort_t* __restrict__ wt, float cw) {
  int idx = blockIdx.x * 256 + threadIdx.x;
  const int total = B_ * 9 * 16 * NF_;
  if (idx >= total) return;
  int ic = idx & 63;
  int ocp = (idx >> 6) & 15;
  int rest = idx >> 10;          // b*9 + kxy
  int kxy = rest % 9;
  int b = rest / 9;
  int ky = kxy / 3, kx = kxy % 3;
  float w = 0.f;
  if (ocp < NC_) w = tw[(((b * NC_ + ocp) * NF_ + ic) * 3 + ky) * 3 + kx] * cw;
  wt[idx] = f2h(w);
}

// ---------- head: 3ch -> 64ch fp32 direct, out NHWC fp16 compact [268][268][64] per slot ----------
__global__ __launch_bounds__(256) void head_k(const float* __restrict__ noise,
        const float* __restrict__ hw, const float* __restrict__ hb,
        ushort_t* __restrict__ out, size_t outStride, float cw, float cb, int b0) {
  const int S = 268;
  int slot = blockIdx.z;
  int b = b0 + slot;
  int x = blockIdx.x * 16 + (threadIdx.x & 15);
  int y = blockIdx.y * 16 + (threadIdx.x >> 4);
  float patch[27];
  const float* nb = noise + (size_t)b * NC_ * HW_ * HW_;
#pragma unroll
  for (int ic = 0; ic < NC_; ic++)
#pragma unroll
    for (int ky = 0; ky < 3; ky++)
#pragma unroll
      for (int kx = 0; kx < 3; kx++) {
        int yy = y + ky - PAD_;
        int xx = x + kx - PAD_;
        float v = 0.f;
        if (yy >= 0 && yy < HW_ && xx >= 0 && xx < HW_)
          v = nb[(size_t)(ic * HW_ + yy) * HW_ + xx];
        patch[ic * 9 + ky * 3 + kx] = v;
      }
  bool valid = (x < S) && (y < S);
  ushort_t* ob = out + (size_t)slot * outStride + ((size_t)y * S + x) * NF_;
  const float* wb = hw + (size_t)b * NF_ * 27;
  const float* bbp = hb + b * NF_;
  for (int oc0 = 0; oc0 < NF_; oc0 += 8) {
    alignas(16) ushort_t h8[8];
#pragma unroll
    for (int u = 0; u < 8; u++) {
      int oc = oc0 + u;
      const float* w = wb + oc * 27;  // block-uniform -> s_load
      float a = 0.f;
#pragma unroll
      for (int j = 0; j < 27; j++) a = fmaf(w[j], patch[j], a);
      a = a * cw + bbp[oc] * cb;
      a = a > 0.f ? a : 0.02f * a;
      h8[u] = f2h(a);
    }
    if (valid) *(uint4*)(ob + oc0) = *(uint4*)h8;
  }
}

// ---------- body v4: weights in LDS, 8 waves/block (8 rows) ----------
// amdgpu_waves_per_eu(4) => VGPR <= 128 => 2 blocks/CU (144KB LDS), 16 waves/CU.
// (__launch_bounds__(512,4) empirically capped VGPR at 64 -> catastrophic spill, r6.)
__global__ __launch_bounds__(512) __attribute__((amdgpu_waves_per_eu(4)))
void body_k(const ushort_t* __restrict__ in, size_t inStride,
        const ushort_t* __restrict__ wt, const float* __restrict__ bb,
        ushort_t* __restrict__ out, size_t outStride, int S, int b0) {
  extern __shared__ ushort_t lw[];   // 36864 halfs = 72 KB, fragment-linear
  const int Sin = S + 2;
  const int slot = blockIdx.y;
  const int b = b0 + slot;
  const int tid = (int)threadIdx.x;
  const int wid = tid >> 6;
  const int lane = tid & 63;
  const int l15 = lane & 15;
  const int l4 = lane >> 4;
  const int y0 = blockIdx.x * 8 + wid;   // output row, one per wave
  const ushort_t* inb = in + (size_t)slot * inStride;

  // stage all 9-tap weights for this batch into LDS (72 KB, once per block)
  {
    const uint4* wsrc = (const uint4*)(wt + (size_t)b * 36864);
    uint4* wdst = (uint4*)lw;
#pragma unroll
    for (int i = 0; i < 9; i++) wdst[tid + i * 512] = wsrc[tid + i * 512];
  }
  __syncthreads();

  float bvv[4];
#pragma unroll
  for (int n = 0; n < 4; n++) bvv[n] = bb[b * NF_ + n * 16 + l15] * 0.125f;

  const f32x4 zero = {0.f, 0.f, 0.f, 0.f};
  const bool rowok = (y0 < S);
  ushort_t* ob = out + (size_t)slot * outStride + (size_t)y0 * S * NF_;

  for (int x0 = 0; x0 < S; x0 += 64) {
    f32x4 acc[4][4];
#pragma unroll
    for (int m = 0; m < 4; m++)
#pragma unroll
      for (int n = 0; n < 4; n++) acc[m][n] = zero;

#pragma unroll
    for (int ky = 0; ky < 3; ky++) {
      int yin = y0 + ky; yin = yin < Sin - 1 ? yin : Sin - 1;
      const ushort_t* rowp = inb + (size_t)yin * Sin * NF_;
#pragma unroll
      for (int kx = 0; kx < 3; kx++) {
#pragma unroll
        for (int k = 0; k < 2; k++) {
          f16x8 a[4];
#pragma unroll
          for (int m = 0; m < 4; m++) {
            int xin = x0 + m * 16 + l15 + kx;
            xin = xin < Sin - 1 ? xin : Sin - 1;
            a[m] = *(const f16x8*)(rowp + (size_t)xin * NF_ + k * 32 + l4 * 8);
          }
          const ushort_t* bp = lw + (((ky * 3 + kx) * 2 + k) * 4) * 512 + lane * 8;
          f16x8 bw0 = *(const f16x8*)(bp);
          f16x8 bw1 = *(const f16x8*)(bp + 512);
          f16x8 bw2 = *(const f16x8*)(bp + 1024);
          f16x8 bw3 = *(const f16x8*)(bp + 1536);
#pragma unroll
          for (int m = 0; m < 4; m++) {
            acc[m][0] = __builtin_amdgcn_mfma_f32_16x16x32_f16(a[m], bw0, acc[m][0], 0, 0, 0);
            acc[m][1] = __builtin_amdgcn_mfma_f32_16x16x32_f16(a[m], bw1, acc[m][1], 0, 0, 0);
            acc[m][2] = __builtin_amdgcn_mfma_f32_16x16x32_f16(a[m], bw2, acc[m][2], 0, 0, 0);
            acc[m][3] = __builtin_amdgcn_mfma_f32_16x16x32_f16(a[m], bw3, acc[m][3], 0, 0, 0);
          }
        }
      }
    }
    if (rowok) {
#pragma unroll
      for (int n = 0; n < 4; n++) {
#pragma unroll
        for (int m = 0; m < 4; m++) {
          int xb = x0 + m * 16 + l4 * 4;
#pragma unroll
          for (int r = 0; r < 4; r++) {
            int x = xb + r;
            if (x < S) {
              float v = acc[m][n][r] + bvv[n];
              v = v > 0.f ? v : 0.02f * v;
              ob[(size_t)x * NF_ + n * 16 + l15] = f2h(v);
            }
          }
        }
      }
    }
  }
}

// ---------- tail: 64->3 (padded to 16) MFMA fp16 + tanh, fp32 NCHW out ----------
__global__ __launch_bounds__(256) void tail_k(const ushort_t* __restrict__ in, size_t inStride,
        const ushort_t* __restrict__ wt, const float* __restrict__ tb,
        float* __restrict__ out, int b0) {
  const int S = 256, Sin = 258;
  const int slot = blockIdx.z;
  const int b = b0 + slot;
  const int wid = (int)(threadIdx.x >> 6);
  const int lane = (int)(threadIdx.x & 63);
  const int l15 = lane & 15;
  const int l4 = lane >> 4;
  const int y0 = blockIdx.y * 4 + wid;
  const int x0 = blockIdx.x * 32;
  const ushort_t* inb = in + (size_t)slot * inStride;
  const ushort_t* wtb = wt + (size_t)b * 9 * 16 * NF_;
  const f32x4 zero = {0.f, 0.f, 0.f, 0.f};
  f32x4 acc[2];
  acc[0] = zero; acc[1] = zero;
#pragma unroll
  for (int ky = 0; ky < 3; ky++) {
    int yin = y0 + ky;                 // <= 257, in range
    const ushort_t* rowp = inb + (size_t)yin * Sin * NF_;
#pragma unroll
    for (int kx = 0; kx < 3; kx++) {
      f16x8 a[2][2];
#pragma unroll
      for (int m = 0; m < 2; m++) {
        int xin = x0 + m * 16 + l15 + kx;  // <= 257, in range
        const ushort_t* p = rowp + (size_t)xin * NF_ + l4 * 8;
        a[m][0] = *(const f16x8*)p;
        a[m][1] = *(const f16x8*)(p + 32);
      }
      const ushort_t* wp = wtb + (ky * 3 + kx) * 16 * NF_ + l15 * NF_ + l4 * 8;
      f16x8 w0 = *(const f16x8*)wp;
      f16x8 w1 = *(const f16x8*)(wp + 32);
#pragma unroll
      for (int m = 0; m < 2; m++) {
        acc[m] = __builtin_amdgcn_mfma_f32_16x16x32_f16(a[m][0], w0, acc[m], 0, 0, 0);
        acc[m] = __builtin_amdgcn_mfma_f32_16x16x32_f16(a[m][1], w1, acc[m], 0, 0, 0);
      }
    }
  }
  if (l15 < NC_) {
    float bv = tb[b * NC_ + l15] * 0.125f;
    float* ob = out + ((size_t)(b * NC_ + l15) * S + y0) * S;
#pragma unroll
    for (int m = 0; m < 2; m++) {
      int xb = x0 + m * 16 + l4 * 4;
#pragma unroll
      for (int r = 0; r < 4; r++) {
        ob[xb + r] = tanhf(acc[m][r] + bv);
      }
    }
  }
}

extern "C" void kernel_launch(void* const* d_in, const int* in_sizes, int n_in,
                              void* d_out, int out_size, void* d_ws, size_t ws_size,
                              hipStream_t stream) {
  const float* noise  = (const float*)d_in[0];
  const float* head_w = (const float*)d_in[1];
  const float* head_b = (const float*)d_in[2];
  const float* body_w = (const float*)d_in[3];
  const float* body_b = (const float*)d_in[4];
  const float* tail_w = (const float*)d_in[5];
  const float* tail_b = (const float*)d_in[6];

  // allow 72 KB dynamic LDS for body_k — unconditional every call (idempotent,
  // host-side, non-stream-ordered: executes immediately, not graph-captured)
  hipFuncSetAttribute((const void*)body_k, hipFuncAttributeMaxDynamicSharedMemorySize, 73728);

  // ws layout: [wt_body 5.90 MB][wt_tail 0.29 MB][act slots: chunk*(bufA 9.19 MB + bufB 9.06 MB)]
  const size_t WT_BODY_ELEMS = (size_t)NL_ * B_ * 9 * NF_ * NF_;   // 2,949,120
  const size_t WT_TAIL_ELEMS = (size_t)B_ * 9 * 16 * NF_;          // 147,456
  const size_t SA_STRIDE = (size_t)268 * 268 * NF_;                // elems per slot, buf A
  const size_t SB_STRIDE = (size_t)266 * 266 * NF_;                // elems per slot, buf B
  ushort_t* wt_body = (ushort_t*)d_ws;
  ushort_t* wt_tail = wt_body + WT_BODY_ELEMS;
  ushort_t* act     = wt_tail + WT_TAIL_ELEMS;

  const size_t wt_bytes   = (WT_BODY_ELEMS + WT_TAIL_ELEMS) * 2;   // ~6.2 MB
  const size_t pair_bytes = (SA_STRIDE + SB_STRIDE) * 2;           // ~18.25 MB per batch
  int chunk = 1;
  if (ws_size > wt_bytes) {
    size_t c = (ws_size - wt_bytes) / pair_bytes;
    chunk = (int)(c < 1 ? 1 : (c > B_ ? B_ : c));
  }
  ushort_t* bufA = act;
  ushort_t* bufB = act + (size_t)chunk * SA_STRIDE;

  const float LRG = sqrtf(2.0f / (1.0f + 0.02f * 0.02f));
  prep_body_k<<<(int)((WT_BODY_ELEMS + 255) / 256), 256, 0, stream>>>(body_w, wt_body, LRG / 24.f);
  prep_tail_k<<<(int)((WT_TAIL_ELEMS + 255) / 256), 256, 0, stream>>>(tail_w, wt_tail, (5.0f / 3.0f) / 24.f);

  for (int b0 = 0; b0 < B_; b0 += chunk) {
    int nb = B_ - b0 < chunk ? B_ - b0 : chunk;
    head_k<<<dim3(17, 17, nb), 256, 0, stream>>>(
        noise, head_w, head_b, bufA, SA_STRIDE, LRG / sqrtf(27.f), 1.0f / sqrtf(3.0f), b0);
    int S = 266;
    const ushort_t* bin = bufA; size_t str_in = SA_STRIDE;
    ushort_t* bout = bufB;      size_t str_out = SB_STRIDE;
    for (int l = 0; l < NL_; l++) {
      body_k<<<dim3((S + 7) / 8, nb), 512, 73728, stream>>>(
          bin, str_in, wt_body + (size_t)l * B_ * 9 * NF_ * NF_, body_b + l * B_ * NF_,
          bout, str_out, S, b0);
      const ushort_t* tp = bin; bin = bout; bout = (ushort_t*)tp;
      size_t ts = str_in; str_in = str_out; str_out = ts;
      S -= 2;
    }
    // after 5 ping-pongs the 258^2 activation sits in bufB (str = SB_STRIDE)
    tail_k<<<dim3(8, 64, nb), 256, 0, stream>>>(bin, str_in, wt_tail, tail_b, (float*)d_out, b0);
  }
}

// Round 8
// 4406.108 us; speedup vs baseline: 1.0031x; 1.0031x over previous
//
#include <hip/hip_runtime.h>
#include <math.h>

typedef unsigned short ushort_t;
typedef _Float16 f16x8 __attribute__((ext_vector_type(8)));
typedef float f32x4 __attribute__((ext_vector_type(4)));

#define B_ 16
#define NC_ 3
#define NF_ 64
#define NL_ 5
#define HW_ 256
#define PAD_ 7

__device__ __forceinline__ ushort_t f2h(float f) {
  union { _Float16 h; ushort_t u; } v;
  v.h = (_Float16)f;           // v_cvt_f16_f32, round-to-nearest-even
  return v.u;
}

// ---------- weight prep: normalize, scale, cast fp16, emit FRAGMENT-LINEAR layout ----------
// wt index = ((((l*16+b)*9 + t)*2 + k)*4 + n)*512 + lane*8 + j
// holding weight[oc = n*16 + (lane&15)][ic = k*32 + (lane>>4)*8 + j] for tap t=(ky*3+kx)
__global__ void prep_body_k(const float* __restrict__ bw, ushort_t* __restrict__ wt, float cw) {
  int idx = blockIdx.x * 256 + threadIdx.x;
  const int total = NL_ * B_ * 9 * 2 * 4 * 64 * 8;
  if (idx >= total) return;
  int j = idx & 7;
  int lane = (idx >> 3) & 63;
  int n = (idx >> 9) & 3;
  int k = (idx >> 11) & 1;
  int rest = idx >> 12;          // (l*16+b)*9 + t
  int t = rest % 9;
  int t2 = rest / 9;
  int b = t2 & 15;
  int l = t2 >> 4;
  int oc = n * 16 + (lane & 15);
  int ic = k * 32 + (lane >> 4) * 8 + j;
  int ky = t / 3, kx = t % 3;
  float w = bw[(((((size_t)l * B_ + b) * NF_ + oc) * NF_ + ic) * 3 + ky) * 3 + kx];
  wt[idx] = f2h(w * cw);
}

__global__ void prep_tail_k(const float* __restrict__ tw, ushort_t* __restrict__ wt, float cw) {
  int idx = blockIdx.x * 256 + threadIdx.x;
  const int total = B_ * 9 * 16 * NF_;
  if (idx >= total) return;
  int ic = idx & 63;
  int ocp = (idx >> 6) & 15;
  int rest = idx >> 10;          // b*9 + kxy
  int kxy = rest % 9;
  int b = rest / 9;
  int ky = kxy / 3, kx = kxy % 3;
  float w = 0.f;
  if (ocp < NC_) w = tw[(((b * NC_ + ocp) * NF_ + ic) * 3 + ky) * 3 + kx] * cw;
  wt[idx] = f2h(w);
}

// ---------- head: 3ch -> 64ch fp32 direct, out NHWC fp16 compact [268][268][64] per slot ----------
__global__ __launch_bounds__(256) void head_k(const float* __restrict__ noise,
        const float* __restrict__ hw, const float* __restrict__ hb,
        ushort_t* __restrict__ out, size_t outStride, float cw, float cb, int b0) {
  const int S = 268;
  int slot = blockIdx.z;
  int b = b0 + slot;
  int x = blockIdx.x * 16 + (threadIdx.x & 15);
  int y = blockIdx.y * 16 + (threadIdx.x >> 4);
  float patch[27];
  const float* nb = noise + (size_t)b * NC_ * HW_ * HW_;
#pragma unroll
  for (int ic = 0; ic < NC_; ic++)
#pragma unroll
    for (int ky = 0; ky < 3; ky++)
#pragma unroll
      for (int kx = 0; kx < 3; kx++) {
        int yy = y + ky - PAD_;
        int xx = x + kx - PAD_;
        float v = 0.f;
        if (yy >= 0 && yy < HW_ && xx >= 0 && xx < HW_)
          v = nb[(size_t)(ic * HW_ + yy) * HW_ + xx];
        patch[ic * 9 + ky * 3 + kx] = v;
      }
  bool valid = (x < S) && (y < S);
  ushort_t* ob = out + (size_t)slot * outStride + ((size_t)y * S + x) * NF_;
  const float* wb = hw + (size_t)b * NF_ * 27;
  const float* bbp = hb + b * NF_;
  for (int oc0 = 0; oc0 < NF_; oc0 += 8) {
    alignas(16) ushort_t h8[8];
#pragma unroll
    for (int u = 0; u < 8; u++) {
      int oc = oc0 + u;
      const float* w = wb + oc * 27;  // block-uniform -> s_load
      float a = 0.f;
#pragma unroll
      for (int j = 0; j < 27; j++) a = fmaf(w[j], patch[j], a);
      a = a * cw + bbp[oc] * cb;
      a = a > 0.f ? a : 0.02f * a;
      h8[u] = f2h(a);
    }
    if (valid) *(uint4*)(ob + oc0) = *(uint4*)h8;
  }
}

// ---------- body v5: weights in LDS, 8 waves/block (8 rows) ----------
// amdgpu_waves_per_eu(4,4): PIN min AND max at 4 waves/EU -> VGPR budget 128.
// History: (512,4) -> VGPR 64 + spill (r6); waves_per_eu(4) min-only -> allocator
// still targeted 8/EU -> VGPR 64 + spill (r7). Max must be pinned.
__global__ __launch_bounds__(512) __attribute__((amdgpu_waves_per_eu(4, 4)))
void body_k(const ushort_t* __restrict__ in, size_t inStride,
        const ushort_t* __restrict__ wt, const float* __restrict__ bb,
        ushort_t* __restrict__ out, size_t outStride, int S, int b0) {
  extern __shared__ ushort_t lw[];   // 36864 halfs = 72 KB, fragment-linear
  const int Sin = S + 2;
  const int slot = blockIdx.y;
  const int b = b0 + slot;
  const int tid = (int)threadIdx.x;
  const int wid = tid >> 6;
  const int lane = tid & 63;
  const int l15 = lane & 15;
  const int l4 = lane >> 4;
  const int y0 = blockIdx.x * 8 + wid;   // output row, one per wave
  const ushort_t* inb = in + (size_t)slot * inStride;

  // stage all 9-tap weights for this batch into LDS (72 KB, once per block)
  {
    const uint4* wsrc = (const uint4*)(wt + (size_t)b * 36864);
    uint4* wdst = (uint4*)lw;
#pragma unroll
    for (int i = 0; i < 9; i++) wdst[tid + i * 512] = wsrc[tid + i * 512];
  }
  __syncthreads();

  float bvv[4];
#pragma unroll
  for (int n = 0; n < 4; n++) bvv[n] = bb[b * NF_ + n * 16 + l15] * 0.125f;

  const f32x4 zero = {0.f, 0.f, 0.f, 0.f};
  const bool rowok = (y0 < S);
  ushort_t* ob = out + (size_t)slot * outStride + (size_t)y0 * S * NF_;

  for (int x0 = 0; x0 < S; x0 += 64) {
    f32x4 acc[4][4];
#pragma unroll
    for (int m = 0; m < 4; m++)
#pragma unroll
      for (int n = 0; n < 4; n++) acc[m][n] = zero;

#pragma unroll
    for (int ky = 0; ky < 3; ky++) {
      int yin = y0 + ky; yin = yin < Sin - 1 ? yin : Sin - 1;
      const ushort_t* rowp = inb + (size_t)yin * Sin * NF_;
#pragma unroll
      for (int kx = 0; kx < 3; kx++) {
#pragma unroll
        for (int k = 0; k < 2; k++) {
          f16x8 a[4];
#pragma unroll
          for (int m = 0; m < 4; m++) {
            int xin = x0 + m * 16 + l15 + kx;
            xin = xin < Sin - 1 ? xin : Sin - 1;
            a[m] = *(const f16x8*)(rowp + (size_t)xin * NF_ + k * 32 + l4 * 8);
          }
          const ushort_t* bp = lw + (((ky * 3 + kx) * 2 + k) * 4) * 512 + lane * 8;
          f16x8 bw0 = *(const f16x8*)(bp);
          f16x8 bw1 = *(const f16x8*)(bp + 512);
          f16x8 bw2 = *(const f16x8*)(bp + 1024);
          f16x8 bw3 = *(const f16x8*)(bp + 1536);
#pragma unroll
          for (int m = 0; m < 4; m++) {
            acc[m][0] = __builtin_amdgcn_mfma_f32_16x16x32_f16(a[m], bw0, acc[m][0], 0, 0, 0);
            acc[m][1] = __builtin_amdgcn_mfma_f32_16x16x32_f16(a[m], bw1, acc[m][1], 0, 0, 0);
            acc[m][2] = __builtin_amdgcn_mfma_f32_16x16x32_f16(a[m], bw2, acc[m][2], 0, 0, 0);
            acc[m][3] = __builtin_amdgcn_mfma_f32_16x16x32_f16(a[m], bw3, acc[m][3], 0, 0, 0);
          }
        }
      }
    }
    if (rowok) {
#pragma unroll
      for (int n = 0; n < 4; n++) {
#pragma unroll
        for (int m = 0; m < 4; m++) {
          int xb = x0 + m * 16 + l4 * 4;
#pragma unroll
          for (int r = 0; r < 4; r++) {
            int x = xb + r;
            if (x < S) {
              float v = acc[m][n][r] + bvv[n];
              v = v > 0.f ? v : 0.02f * v;
              ob[(size_t)x * NF_ + n * 16 + l15] = f2h(v);
            }
          }
        }
      }
    }
  }
}

// ---------- tail: 64->3 (padded to 16) MFMA fp16 + tanh, fp32 NCHW out ----------
__global__ __launch_bounds__(256) void tail_k(const ushort_t* __restrict__ in, size_t inStride,
        const ushort_t* __restrict__ wt, const float* __restrict__ tb,
        float* __restrict__ out, int b0) {
  const int S = 256, Sin = 258;
  const int slot = blockIdx.z;
  const int b = b0 + slot;
  const int wid = (int)(threadIdx.x >> 6);
  const int lane = (int)(threadIdx.x & 63);
  const int l15 = lane & 15;
  const int l4 = lane >> 4;
  const int y0 = blockIdx.y * 4 + wid;
  const int x0 = blockIdx.x * 32;
  const ushort_t* inb = in + (size_t)slot * inStride;
  const ushort_t* wtb = wt + (size_t)b * 9 * 16 * NF_;
  const f32x4 zero = {0.f, 0.f, 0.f, 0.f};
  f32x4 acc[2];
  acc[0] = zero; acc[1] = zero;
#pragma unroll
  for (int ky = 0; ky < 3; ky++) {
    int yin = y0 + ky;                 // <= 257, in range
    const ushort_t* rowp = inb + (size_t)yin * Sin * NF_;
#pragma unroll
    for (int kx = 0; kx < 3; kx++) {
      f16x8 a[2][2];
#pragma unroll
      for (int m = 0; m < 2; m++) {
        int xin = x0 + m * 16 + l15 + kx;  // <= 257, in range
        const ushort_t* p = rowp + (size_t)xin * NF_ + l4 * 8;
        a[m][0] = *(const f16x8*)p;
        a[m][1] = *(const f16x8*)(p + 32);
      }
      const ushort_t* wp = wtb + (ky * 3 + kx) * 16 * NF_ + l15 * NF_ + l4 * 8;
      f16x8 w0 = *(const f16x8*)wp;
      f16x8 w1 = *(const f16x8*)(wp + 32);
#pragma unroll
      for (int m = 0; m < 2; m++) {
        acc[m] = __builtin_amdgcn_mfma_f32_16x16x32_f16(a[m][0], w0, acc[m], 0, 0, 0);
        acc[m] = __builtin_amdgcn_mfma_f32_16x16x32_f16(a[m][1], w1, acc[m], 0, 0, 0);
      }
    }
  }
  if (l15 < NC_) {
    float bv = tb[b * NC_ + l15] * 0.125f;
    float* ob = out + ((size_t)(b * NC_ + l15) * S + y0) * S;
#pragma unroll
    for (int m = 0; m < 2; m++) {
      int xb = x0 + m * 16 + l4 * 4;
#pragma unroll
      for (int r = 0; r < 4; r++) {
        ob[xb + r] = tanhf(acc[m][r] + bv);
      }
    }
  }
}

extern "C" void kernel_launch(void* const* d_in, const int* in_sizes, int n_in,
                              void* d_out, int out_size, void* d_ws, size_t ws_size,
                              hipStream_t stream) {
  const float* noise  = (const float*)d_in[0];
  const float* head_w = (const float*)d_in[1];
  const float* head_b = (const float*)d_in[2];
  const float* body_w = (const float*)d_in[3];
  const float* body_b = (const float*)d_in[4];
  const float* tail_w = (const float*)d_in[5];
  const float* tail_b = (const float*)d_in[6];

  // allow 72 KB dynamic LDS for body_k — unconditional every call (idempotent,
  // host-side, non-stream-ordered: executes immediately, not graph-captured)
  hipFuncSetAttribute((const void*)body_k, hipFuncAttributeMaxDynamicSharedMemorySize, 73728);

  // ws layout: [wt_body 5.90 MB][wt_tail 0.29 MB][act slots: chunk*(bufA 9.19 MB + bufB 9.06 MB)]
  const size_t WT_BODY_ELEMS = (size_t)NL_ * B_ * 9 * NF_ * NF_;   // 2,949,120
  const size_t WT_TAIL_ELEMS = (size_t)B_ * 9 * 16 * NF_;          // 147,456
  const size_t SA_STRIDE = (size_t)268 * 268 * NF_;                // elems per slot, buf A
  const size_t SB_STRIDE = (size_t)266 * 266 * NF_;                // elems per slot, buf B
  ushort_t* wt_body = (ushort_t*)d_ws;
  ushort_t* wt_tail = wt_body + WT_BODY_ELEMS;
  ushort_t* act     = wt_tail + WT_TAIL_ELEMS;

  const size_t wt_bytes   = (WT_BODY_ELEMS + WT_TAIL_ELEMS) * 2;   // ~6.2 MB
  const size_t pair_bytes = (SA_STRIDE + SB_STRIDE) * 2;           // ~18.25 MB per batch
  int chunk = 1;
  if (ws_size > wt_bytes) {
    size_t c = (ws_size - wt_bytes) / pair_bytes;
    chunk = (int)(c < 1 ? 1 : (c > B_ ? B_ : c));
  }
  ushort_t* bufA = act;
  ushort_t* bufB = act + (size_t)chunk * SA_STRIDE;

  const float LRG = sqrtf(2.0f / (1.0f + 0.02f * 0.02f));
  prep_body_k<<<(int)((WT_BODY_ELEMS + 255) / 256), 256, 0, stream>>>(body_w, wt_body, LRG / 24.f);
  prep_tail_k<<<(int)((WT_TAIL_ELEMS + 255) / 256), 256, 0, stream>>>(tail_w, wt_tail, (5.0f / 3.0f) / 24.f);

  for (int b0 = 0; b0 < B_; b0 += chunk) {
    int nb = B_ - b0 < chunk ? B_ - b0 : chunk;
    head_k<<<dim3(17, 17, nb), 256, 0, stream>>>(
        noise, head_w, head_b, bufA, SA_STRIDE, LRG / sqrtf(27.f), 1.0f / sqrtf(3.0f), b0);
    int S = 266;
    const ushort_t* bin = bufA; size_t str_in = SA_STRIDE;
    ushort_t* bout = bufB;      size_t str_out = SB_STRIDE;
    for (int l = 0; l < NL_; l++) {
      body_k<<<dim3((S + 7) / 8, nb), 512, 73728, stream>>>(
          bin, str_in, wt_body + (size_t)l * B_ * 9 * NF_ * NF_, body_b + l * B_ * NF_,
          bout, str_out, S, b0);
      const ushort_t* tp = bin; bin = bout; bout = (ushort_t*)tp;
      size_t ts = str_in; str_in = str_out; str_out = ts;
      S -= 2;
    }
    // after 5 ping-pongs the 258^2 activation sits in bufB (str = SB_STRIDE)
    tail_k<<<dim3(8, 64, nb), 256, 0, stream>>>(bin, str_in, wt_tail, tail_b, (float*)d_out, b0);
  }
}

// Round 9
// 1783.018 us; speedup vs baseline: 2.4789x; 2.4712x over previous
//
#include <hip/hip_runtime.h>
#include <math.h>

typedef unsigned short ushort_t;
typedef _Float16 f16x8 __attribute__((ext_vector_type(8)));
typedef float f32x4 __attribute__((ext_vector_type(4)));

#define B_ 16
#define NC_ 3
#define NF_ 64
#define NL_ 5
#define HW_ 256
#define PAD_ 7

__device__ __forceinline__ ushort_t f2h(float f) {
  union { _Float16 h; ushort_t u; } v;
  v.h = (_Float16)f;           // v_cvt_f16_f32, round-to-nearest-even
  return v.u;
}

// ---------- weight prep: normalize, scale, cast fp16, emit FRAGMENT-LINEAR layout ----------
// wt index = ((((l*16+b)*9 + t)*2 + k)*4 + n)*512 + lane*8 + j
// holding weight[oc = n*16 + (lane&15)][ic = k*32 + (lane>>4)*8 + j] for tap t=(ky*3+kx)
__global__ void prep_body_k(const float* __restrict__ bw, ushort_t* __restrict__ wt, float cw) {
  int idx = blockIdx.x * 256 + threadIdx.x;
  const int total = NL_ * B_ * 9 * 2 * 4 * 64 * 8;
  if (idx >= total) return;
  int j = idx & 7;
  int lane = (idx >> 3) & 63;
  int n = (idx >> 9) & 3;
  int k = (idx >> 11) & 1;
  int rest = idx >> 12;          // (l*16+b)*9 + t
  int t = rest % 9;
  int t2 = rest / 9;
  int b = t2 & 15;
  int l = t2 >> 4;
  int oc = n * 16 + (lane & 15);
  int ic = k * 32 + (lane >> 4) * 8 + j;
  int ky = t / 3, kx = t % 3;
  float w = bw[(((((size_t)l * B_ + b) * NF_ + oc) * NF_ + ic) * 3 + ky) * 3 + kx];
  wt[idx] = f2h(w * cw);
}

__global__ void prep_tail_k(const float* __restrict__ tw, ushort_t* __restrict__ wt, float cw) {
  int idx = blockIdx.x * 256 + threadIdx.x;
  const int total = B_ * 9 * 16 * NF_;
  if (idx >= total) return;
  int ic = idx & 63;
  int ocp = (idx >> 6) & 15;
  int rest = idx >> 10;          // b*9 + kxy
  int kxy = rest % 9;
  int b = rest / 9;
  int ky = kxy / 3, kx = kxy % 3;
  float w = 0.f;
  if (ocp < NC_) w = tw[(((b * NC_ + ocp) * NF_ + ic) * 3 + ky) * 3 + kx] * cw;
  wt[idx] = f2h(w);
}

// ---------- head: 3ch -> 64ch fp32 direct, out NHWC fp16 compact [268][268][64] per slot ----------
__global__ __launch_bounds__(256) void head_k(const float* __restrict__ noise,
        const float* __restrict__ hw, const float* __restrict__ hb,
        ushort_t* __restrict__ out, size_t outStride, float cw, float cb, int b0) {
  const int S = 268;
  int slot = blockIdx.z;
  int b = b0 + slot;
  int x = blockIdx.x * 16 + (threadIdx.x & 15);
  int y = blockIdx.y * 16 + (threadIdx.x >> 4);
  float patch[27];
  const float* nb = noise + (size_t)b * NC_ * HW_ * HW_;
#pragma unroll
  for (int ic = 0; ic < NC_; ic++)
#pragma unroll
    for (int ky = 0; ky < 3; ky++)
#pragma unroll
      for (int kx = 0; kx < 3; kx++) {
        int yy = y + ky - PAD_;
        int xx = x + kx - PAD_;
        float v = 0.f;
        if (yy >= 0 && yy < HW_ && xx >= 0 && xx < HW_)
          v = nb[(size_t)(ic * HW_ + yy) * HW_ + xx];
        patch[ic * 9 + ky * 3 + kx] = v;
      }
  bool valid = (x < S) && (y < S);
  ushort_t* ob = out + (size_t)slot * outStride + ((size_t)y * S + x) * NF_;
  const float* wb = hw + (size_t)b * NF_ * 27;
  const float* bbp = hb + b * NF_;
  for (int oc0 = 0; oc0 < NF_; oc0 += 8) {
    alignas(16) ushort_t h8[8];
#pragma unroll
    for (int u = 0; u < 8; u++) {
      int oc = oc0 + u;
      const float* w = wb + oc * 27;  // block-uniform -> s_load
      float a = 0.f;
#pragma unroll
      for (int j = 0; j < 27; j++) a = fmaf(w[j], patch[j], a);
      a = a * cw + bbp[oc] * cb;
      a = a > 0.f ? a : 0.02f * a;
      h8[u] = f2h(a);
    }
    if (valid) *(uint4*)(ob + oc0) = *(uint4*)h8;
  }
}

// ---------- body v6: weights in LDS, 8 waves/block (8 rows) ----------
// __launch_bounds__(512, 2): empirically arg2 behaves CUDA-style (min BLOCKS/CU):
//   r6 (512,4) -> 4 blk/CU = 32 waves/CU -> VGPR 64 -> spill (1.2GB FETCH/layer).
//   (512,2) -> 2 blk/CU = 16 waves/CU = 4 waves/SIMD -> VGPR budget 128. Demand ~116.
// #pragma unroll 1 on ky: limit scheduler load-hoisting window (r5: hoisting
// across 9 unrolled taps bloated VGPR to 216).
__global__ __launch_bounds__(512, 2)
void body_k(const ushort_t* __restrict__ in, size_t inStride,
        const ushort_t* __restrict__ wt, const float* __restrict__ bb,
        ushort_t* __restrict__ out, size_t outStride, int S, int b0) {
  extern __shared__ ushort_t lw[];   // 36864 halfs = 72 KB, fragment-linear
  const int Sin = S + 2;
  const int slot = blockIdx.y;
  const int b = b0 + slot;
  const int tid = (int)threadIdx.x;
  const int wid = tid >> 6;
  const int lane = tid & 63;
  const int l15 = lane & 15;
  const int l4 = lane >> 4;
  const int y0 = blockIdx.x * 8 + wid;   // output row, one per wave
  const ushort_t* inb = in + (size_t)slot * inStride;

  // stage all 9-tap weights for this batch into LDS (72 KB, once per block)
  {
    const uint4* wsrc = (const uint4*)(wt + (size_t)b * 36864);
    uint4* wdst = (uint4*)lw;
#pragma unroll
    for (int i = 0; i < 9; i++) wdst[tid + i * 512] = wsrc[tid + i * 512];
  }
  __syncthreads();

  float bvv[4];
#pragma unroll
  for (int n = 0; n < 4; n++) bvv[n] = bb[b * NF_ + n * 16 + l15] * 0.125f;

  const f32x4 zero = {0.f, 0.f, 0.f, 0.f};
  const bool rowok = (y0 < S);
  ushort_t* ob = out + (size_t)slot * outStride + (size_t)y0 * S * NF_;

  for (int x0 = 0; x0 < S; x0 += 64) {
    f32x4 acc[4][4];
#pragma unroll
    for (int m = 0; m < 4; m++)
#pragma unroll
      for (int n = 0; n < 4; n++) acc[m][n] = zero;

#pragma unroll 1
    for (int ky = 0; ky < 3; ky++) {
      int yin = y0 + ky; yin = yin < Sin - 1 ? yin : Sin - 1;
      const ushort_t* rowp = inb + (size_t)yin * Sin * NF_;
#pragma unroll
      for (int kx = 0; kx < 3; kx++) {
#pragma unroll
        for (int k = 0; k < 2; k++) {
          f16x8 a[4];
#pragma unroll
          for (int m = 0; m < 4; m++) {
            int xin = x0 + m * 16 + l15 + kx;
            xin = xin < Sin - 1 ? xin : Sin - 1;
            a[m] = *(const f16x8*)(rowp + (size_t)xin * NF_ + k * 32 + l4 * 8);
          }
          const ushort_t* bp = lw + (((ky * 3 + kx) * 2 + k) * 4) * 512 + lane * 8;
          f16x8 bw0 = *(const f16x8*)(bp);
          f16x8 bw1 = *(const f16x8*)(bp + 512);
          f16x8 bw2 = *(const f16x8*)(bp + 1024);
          f16x8 bw3 = *(const f16x8*)(bp + 1536);
#pragma unroll
          for (int m = 0; m < 4; m++) {
            acc[m][0] = __builtin_amdgcn_mfma_f32_16x16x32_f16(a[m], bw0, acc[m][0], 0, 0, 0);
            acc[m][1] = __builtin_amdgcn_mfma_f32_16x16x32_f16(a[m], bw1, acc[m][1], 0, 0, 0);
            acc[m][2] = __builtin_amdgcn_mfma_f32_16x16x32_f16(a[m], bw2, acc[m][2], 0, 0, 0);
            acc[m][3] = __builtin_amdgcn_mfma_f32_16x16x32_f16(a[m], bw3, acc[m][3], 0, 0, 0);
          }
        }
      }
    }
    if (rowok) {
#pragma unroll
      for (int n = 0; n < 4; n++) {
#pragma unroll
        for (int m = 0; m < 4; m++) {
          int xb = x0 + m * 16 + l4 * 4;
#pragma unroll
          for (int r = 0; r < 4; r++) {
            int x = xb + r;
            if (x < S) {
              float v = acc[m][n][r] + bvv[n];
              v = v > 0.f ? v : 0.02f * v;
              ob[(size_t)x * NF_ + n * 16 + l15] = f2h(v);
            }
          }
        }
      }
    }
  }
}

// ---------- tail: 64->3 (padded to 16) MFMA fp16 + tanh, fp32 NCHW out ----------
__global__ __launch_bounds__(256) void tail_k(const ushort_t* __restrict__ in, size_t inStride,
        const ushort_t* __restrict__ wt, const float* __restrict__ tb,
        float* __restrict__ out, int b0) {
  const int S = 256, Sin = 258;
  const int slot = blockIdx.z;
  const int b = b0 + slot;
  const int wid = (int)(threadIdx.x >> 6);
  const int lane = (int)(threadIdx.x & 63);
  const int l15 = lane & 15;
  const int l4 = lane >> 4;
  const int y0 = blockIdx.y * 4 + wid;
  const int x0 = blockIdx.x * 32;
  const ushort_t* inb = in + (size_t)slot * inStride;
  const ushort_t* wtb = wt + (size_t)b * 9 * 16 * NF_;
  const f32x4 zero = {0.f, 0.f, 0.f, 0.f};
  f32x4 acc[2];
  acc[0] = zero; acc[1] = zero;
#pragma unroll
  for (int ky = 0; ky < 3; ky++) {
    int yin = y0 + ky;                 // <= 257, in range
    const ushort_t* rowp = inb + (size_t)yin * Sin * NF_;
#pragma unroll
    for (int kx = 0; kx < 3; kx++) {
      f16x8 a[2][2];
#pragma unroll
      for (int m = 0; m < 2; m++) {
        int xin = x0 + m * 16 + l15 + kx;  // <= 257, in range
        const ushort_t* p = rowp + (size_t)xin * NF_ + l4 * 8;
        a[m][0] = *(const f16x8*)p;
        a[m][1] = *(const f16x8*)(p + 32);
      }
      const ushort_t* wp = wtb + (ky * 3 + kx) * 16 * NF_ + l15 * NF_ + l4 * 8;
      f16x8 w0 = *(const f16x8*)wp;
      f16x8 w1 = *(const f16x8*)(wp + 32);
#pragma unroll
      for (int m = 0; m < 2; m++) {
        acc[m] = __builtin_amdgcn_mfma_f32_16x16x32_f16(a[m][0], w0, acc[m], 0, 0, 0);
        acc[m] = __builtin_amdgcn_mfma_f32_16x16x32_f16(a[m][1], w1, acc[m], 0, 0, 0);
      }
    }
  }
  if (l15 < NC_) {
    float bv = tb[b * NC_ + l15] * 0.125f;
    float* ob = out + ((size_t)(b * NC_ + l15) * S + y0) * S;
#pragma unroll
    for (int m = 0; m < 2; m++) {
      int xb = x0 + m * 16 + l4 * 4;
#pragma unroll
      for (int r = 0; r < 4; r++) {
        ob[xb + r] = tanhf(acc[m][r] + bv);
      }
    }
  }
}

extern "C" void kernel_launch(void* const* d_in, const int* in_sizes, int n_in,
                              void* d_out, int out_size, void* d_ws, size_t ws_size,
                              hipStream_t stream) {
  const float* noise  = (const float*)d_in[0];
  const float* head_w = (const float*)d_in[1];
  const float* head_b = (const float*)d_in[2];
  const float* body_w = (const float*)d_in[3];
  const float* body_b = (const float*)d_in[4];
  const float* tail_w = (const float*)d_in[5];
  const float* tail_b = (const float*)d_in[6];

  // allow 72 KB dynamic LDS for body_k — unconditional every call (idempotent,
  // host-side, non-stream-ordered: executes immediately, not graph-captured)
  hipFuncSetAttribute((const void*)body_k, hipFuncAttributeMaxDynamicSharedMemorySize, 73728);

  // ws layout: [wt_body 5.90 MB][wt_tail 0.29 MB][act slots: chunk*(bufA 9.19 MB + bufB 9.06 MB)]
  const size_t WT_BODY_ELEMS = (size_t)NL_ * B_ * 9 * NF_ * NF_;   // 2,949,120
  const size_t WT_TAIL_ELEMS = (size_t)B_ * 9 * 16 * NF_;          // 147,456
  const size_t SA_STRIDE = (size_t)268 * 268 * NF_;                // elems per slot, buf A
  const size_t SB_STRIDE = (size_t)266 * 266 * NF_;                // elems per slot, buf B
  ushort_t* wt_body = (ushort_t*)d_ws;
  ushort_t* wt_tail = wt_body + WT_BODY_ELEMS;
  ushort_t* act     = wt_tail + WT_TAIL_ELEMS;

  const size_t wt_bytes   = (WT_BODY_ELEMS + WT_TAIL_ELEMS) * 2;   // ~6.2 MB
  const size_t pair_bytes = (SA_STRIDE + SB_STRIDE) * 2;           // ~18.25 MB per batch
  int chunk = 1;
  if (ws_size > wt_bytes) {
    size_t c = (ws_size - wt_bytes) / pair_bytes;
    chunk = (int)(c < 1 ? 1 : (c > B_ ? B_ : c));
  }
  ushort_t* bufA = act;
  ushort_t* bufB = act + (size_t)chunk * SA_STRIDE;

  const float LRG = sqrtf(2.0f / (1.0f + 0.02f * 0.02f));
  prep_body_k<<<(int)((WT_BODY_ELEMS + 255) / 256), 256, 0, stream>>>(body_w, wt_body, LRG / 24.f);
  prep_tail_k<<<(int)((WT_TAIL_ELEMS + 255) / 256), 256, 0, stream>>>(tail_w, wt_tail, (5.0f / 3.0f) / 24.f);

  for (int b0 = 0; b0 < B_; b0 += chunk) {
    int nb = B_ - b0 < chunk ? B_ - b0 : chunk;
    head_k<<<dim3(17, 17, nb), 256, 0, stream>>>(
        noise, head_w, head_b, bufA, SA_STRIDE, LRG / sqrtf(27.f), 1.0f / sqrtf(3.0f), b0);
    int S = 266;
    const ushort_t* bin = bufA; size_t str_in = SA_STRIDE;
    ushort_t* bout = bufB;      size_t str_out = SB_STRIDE;
    for (int l = 0; l < NL_; l++) {
      body_k<<<dim3((S + 7) / 8, nb), 512, 73728, stream>>>(
          bin, str_in, wt_body + (size_t)l * B_ * 9 * NF_ * NF_, body_b + l * B_ * NF_,
          bout, str_out, S, b0);
      const ushort_t* tp = bin; bin = bout; bout = (ushort_t*)tp;
      size_t ts = str_in; str_in = str_out; str_out = ts;
      S -= 2;
    }
    // after 5 ping-pongs the 258^2 activation sits in bufB (str = SB_STRIDE)
    tail_k<<<dim3(8, 64, nb), 256, 0, stream>>>(bin, str_in, wt_tail, tail_b, (float*)d_out, b0);
  }
}